// Round 2
// baseline (15415.285 us; speedup 1.0000x reference)
//
#include <hip/hip_runtime.h>
#include <hip/hip_cooperative_groups.h>

namespace cg = cooperative_groups;

typedef __bf16 bf16;
typedef __bf16 bf16x8 __attribute__((ext_vector_type(8)));
typedef float f32x4 __attribute__((ext_vector_type(4)));

#define Bsz 256
#define Tsz 256
#define Dsz 128
#define Hsz 384
#define Lsz 12
#define Gsz 1560
#define Ksz 512
#define STR 520      // padded k-stride (elems)
#define NCOL 128     // padded per-WG columns (120 real)
#define CST 132      // C_lds row stride (fp32 elems)
#define MT 16        // batches per WG
#define JT 24        // channels per WG

// LDS layout (bytes)
#define OFF_B   0
#define OFF_A   (NCOL*STR*2)              // 133120
#define OFF_FM  (OFF_A + MT*STR*2)        // +16640
#define OFF_IM  (OFF_FM + MT*Lsz*4)
#define OFF_TB  (OFF_IM + MT*Lsz*4)
#define OFF_WL  (OFF_TB + MT*4)
#define OFF_BI  (OFF_WL + NCOL*4)
#define OFF_CS  (OFF_BI + NCOL*4)
#define SMEM_BYTES (OFF_CS + MT*JT*4)     // 153920

__device__ __forceinline__ int map_gcol(int col, int jb) {
    if (col < 24) return col;              // master logit columns 0..23
    int r = col - 24;
    int blk = r / 24;                      // 0=f,1=i,2=o,3=cin
    int jj = r - blk * 24;
    return 24 + blk * Hsz + jb + jj;
}

__device__ __forceinline__ float sigm(float v) { return 1.0f / (1.0f + expf(-v)); }

__device__ __forceinline__ float ldf(const void* p, size_t i, bool f32) {
    return f32 ? ((const float*)p)[i] : (float)((const bf16*)p)[i];
}

__global__ __launch_bounds__(256) void stagenet_kernel(
    const void* __restrict__ x, const void* __restrict__ tim,
    const void* __restrict__ Wk, const void* __restrict__ bk,
    const void* __restrict__ Wr, const void* __restrict__ br,
    void* __restrict__ out)
{
    extern __shared__ char smem[];
    bf16*  Bl = (bf16*)(smem + OFF_B);
    bf16*  Al = (bf16*)(smem + OFF_A);
    float* Cl = (float*)(smem + OFF_A);   // aliases Al (after GEMM reads done)
    float* FM = (float*)(smem + OFF_FM);
    float* IM = (float*)(smem + OFF_IM);
    float* TB = (float*)(smem + OFF_TB);
    float* WL = (float*)(smem + OFF_WL);
    float* BI = (float*)(smem + OFF_BI);
    float* CS = (float*)(smem + OFF_CS);

    const int tid = threadIdx.x;
    const int wg  = blockIdx.x;
    const int mg  = wg >> 4;
    const int ng  = wg & 15;
    const int b0  = mg * MT;
    const int jb  = ng * JT;

    // ---- runtime dtype detection (wave-uniform): fp32 read as bf16 has
    // random exponents in the low halves; genuine bf16 weights are sane ----
    int insane = 0;
    {
        const unsigned short* wb = (const unsigned short*)Wk;
        for (int i = 0; i < 64; ++i) {
            unsigned short u = wb[i];
            int e = (u >> 7) & 0xFF;
            if ((e < 90 || e > 140) && u != 0) insane++;
        }
    }
    const bool isF32 = insane > 8;

    // ---- one-time: weight slice -> LDS bf16, B[n][k] layout ----
    for (int u = tid; u < NCOL * Ksz; u += 256) {
        int col = u & (NCOL - 1);
        int k   = u >> 7;
        bf16 v = (bf16)0.0f;
        if (col < 120) {
            int gcol = map_gcol(col, jb);
            float f = (k < Dsz) ? ldf(Wk, (size_t)k * Gsz + gcol, isF32)
                                : ldf(Wr, (size_t)(k - Dsz) * Gsz + gcol, isF32);
            v = (bf16)f;
        }
        Bl[col * STR + k] = v;
    }
    for (int col = tid; col < NCOL; col += 256) {
        float wl = 0.f, bi = 0.f;
        if (col < 120) {
            int gcol = map_gcol(col, jb);
            wl = ldf(Wk, (size_t)Dsz * Gsz + gcol, isF32) + ldf(Wr, (size_t)Hsz * Gsz + gcol, isF32);
            bi = ldf(bk, gcol, isF32) + ldf(br, gcol, isF32);
        }
        WL[col] = wl; BI[col] = bi;
    }
    for (int i = tid; i < MT * JT; i += 256) CS[i] = 0.f;

    cg::grid_group grid = cg::this_grid();
    grid.sync();

    const int lane = tid & 63;
    const int wv   = tid >> 6;
    const int m16  = lane & 15;
    const int quad = lane >> 4;
    const int n0   = (2 * wv) * 16 + m16;
    const int n1   = (2 * wv + 1) * 16 + m16;

    for (int t = 0; t < Tsz; ++t) {
        // ---- stage A = [x_t | h_{t-1}] (16 x 512) as bf16; h lives in out ----
        for (int u = tid; u < MT * 64; u += 256) {
            int m = u >> 6, q = u & 63;
            bf16x8 val;
            if (q < 16) {
                size_t base = ((size_t)(b0 + m) * Tsz + t) * Dsz + q * 8;
                if (isF32) {
                    const float* s = (const float*)x + base;
                    #pragma unroll
                    for (int j = 0; j < 8; ++j) val[j] = (bf16)s[j];
                } else {
                    val = *(const bf16x8*)((const bf16*)x + base);
                }
            } else if (t == 0) {
                #pragma unroll
                for (int j = 0; j < 8; ++j) val[j] = (bf16)0.0f;
            } else {
                size_t base = ((size_t)(b0 + m) * Tsz + (t - 1)) * Hsz + (q - 16) * 8;
                if (isF32) {
                    const float* s = (const float*)out + base;
                    #pragma unroll
                    for (int j = 0; j < 8; ++j) val[j] = (bf16)s[j];
                } else {
                    val = *(const bf16x8*)((const bf16*)out + base);
                }
            }
            *(bf16x8*)(Al + m * STR + q * 8) = val;
        }
        if (tid < MT) TB[tid] = ldf(tim, (size_t)(b0 + tid) * Tsz + t, isF32);
        __syncthreads();

        // ---- GEMM (16x512)@(512x128): 4 waves x 2 N-tiles ----
        f32x4 a0 = {0.f, 0.f, 0.f, 0.f}, a1 = {0.f, 0.f, 0.f, 0.f};
        #pragma unroll
        for (int ks = 0; ks < 16; ++ks) {
            bf16x8 av  = *(const bf16x8*)(Al + m16 * STR + ks * 32 + quad * 8);
            bf16x8 bv0 = *(const bf16x8*)(Bl + n0 * STR + ks * 32 + quad * 8);
            bf16x8 bv1 = *(const bf16x8*)(Bl + n1 * STR + ks * 32 + quad * 8);
            a0 = __builtin_amdgcn_mfma_f32_16x16x32_bf16(av, bv0, a0, 0, 0, 0);
            a1 = __builtin_amdgcn_mfma_f32_16x16x32_bf16(av, bv1, a1, 0, 0, 0);
        }
        __syncthreads();   // all A/B LDS reads done before aliased C write

        #pragma unroll
        for (int r = 0; r < 4; ++r) {
            Cl[(quad * 4 + r) * CST + (2 * wv) * 16 + m16]     = a0[r];
            Cl[(quad * 4 + r) * CST + (2 * wv + 1) * 16 + m16] = a1[r];
        }
        __syncthreads();

        // ---- masters: softmax + cumsum over L=12, one thread per batch ----
        if (tid < MT) {
            const int m = tid;
            const float tb = TB[m];
            float z[24];
            #pragma unroll
            for (int i = 0; i < 24; ++i)
                z[i] = Cl[m * CST + i] + BI[i] + tb * WL[i];
            float mx = z[0];
            #pragma unroll
            for (int i = 1; i < 12; ++i) mx = fmaxf(mx, z[i]);
            float e[12], s = 0.f;
            #pragma unroll
            for (int i = 0; i < 12; ++i) { e[i] = expf(z[i] - mx); s += e[i]; }
            float inv = 1.f / s, run = 0.f;
            #pragma unroll
            for (int i = 0; i < 12; ++i) { run += e[i]; FM[m * Lsz + i] = run * inv; }
            mx = z[12];
            #pragma unroll
            for (int i = 13; i < 24; ++i) mx = fmaxf(mx, z[i]);
            s = 0.f;
            #pragma unroll
            for (int i = 0; i < 12; ++i) { e[i] = expf(z[12 + i] - mx); s += e[i]; }
            inv = 1.f / s; run = 0.f;
            #pragma unroll
            for (int i = 11; i >= 0; --i) { run += e[i]; IM[m * Lsz + i] = run * inv; }
        }
        __syncthreads();

        // ---- gates + state update: 16 batches x 24 channels ----
        for (int fi = tid; fi < MT * JT; fi += 256) {
            int m = fi / JT;
            int j = fi - m * JT;
            int gj = jb + j;
            int l = gj >> 5;               // C = 32
            float tb = TB[m];
            float vf = Cl[m * CST + 24 + j] + BI[24 + j] + tb * WL[24 + j];
            float vi = Cl[m * CST + 48 + j] + BI[48 + j] + tb * WL[48 + j];
            float vo = Cl[m * CST + 72 + j] + BI[72 + j] + tb * WL[72 + j];
            float vc = Cl[m * CST + 96 + j] + BI[96 + j] + tb * WL[96 + j];
            float fg = sigm(vf);
            float ig = sigm(vi);
            float og = sigm(vo);
            float ci = tanhf(vc);
            float fm = FM[m * Lsz + l];
            float im = IM[m * Lsz + l];
            float ov = fm * im;
            float co = CS[fi];
            float cn = ov * (fg * co + ig * ci) + (fm - ov) * co + (im - ov) * ci;
            CS[fi] = cn;
            float hv = og * tanhf(cn);
            size_t oidx = ((size_t)(b0 + m) * Tsz + t) * Hsz + gj;
            if (isF32) ((float*)out)[oidx] = hv;
            else       ((bf16*)out)[oidx] = (bf16)hv;
        }
        __threadfence();
        grid.sync();
    }
}

extern "C" void kernel_launch(void* const* d_in, const int* in_sizes, int n_in,
                              void* d_out, int out_size, void* d_ws, size_t ws_size,
                              hipStream_t stream) {
    const void* x  = d_in[0];
    const void* tm = d_in[1];
    const void* Wk = d_in[2];
    const void* bk = d_in[3];
    const void* Wr = d_in[4];
    const void* br = d_in[5];

    hipFuncSetAttribute(reinterpret_cast<const void*>(&stagenet_kernel),
                        hipFuncAttributeMaxDynamicSharedMemorySize, SMEM_BYTES);

    void* args[] = {(void*)&x, (void*)&tm, (void*)&Wk, (void*)&bk,
                    (void*)&Wr, (void*)&br, (void*)&d_out};
    hipLaunchCooperativeKernel(stagenet_kernel, dim3(256), dim3(256),
                               args, SMEM_BYTES, stream);
}

// Round 5
// 3238.819 us; speedup vs baseline: 4.7595x; 4.7595x over previous
//
#include <hip/hip_runtime.h>
#include <hip/hip_cooperative_groups.h>

namespace cg = cooperative_groups;

typedef __bf16 bf16;
typedef __bf16 bf16x8 __attribute__((ext_vector_type(8)));
typedef float f32x4 __attribute__((ext_vector_type(4)));

#define Bsz 256
#define Tsz 256
#define Dsz 128
#define Hsz 384
#define Lsz 12
#define Gsz 1560
#define Ksz 512
#define STR 520      // padded k-stride (elems)
#define NCOL 128     // padded per-WG columns (120 real)
#define CST 132      // C_lds row stride (fp32 elems)
#define MT 16        // batches per WG
#define JT 24        // channels per WG
#define FSTRIDE 32   // flag stride in dwords (128B, avoid false sharing)

// LDS layout (bytes)
#define OFF_B   0
#define OFF_A   (NCOL*STR*2)              // 133120
#define OFF_FM  (OFF_A + MT*STR*2)        // +16640
#define OFF_IM  (OFF_FM + MT*Lsz*4)
#define OFF_TB  (OFF_IM + MT*Lsz*4)
#define OFF_WL  (OFF_TB + MT*4)
#define OFF_BI  (OFF_WL + NCOL*4)
#define OFF_CS  (OFF_BI + NCOL*4)
#define SMEM_BYTES (OFF_CS + MT*JT*4)     // 153920

// Flags in module .bss — no d_ws dependence, survives graph replay (re-zeroed
// at the top of every launch before the one-time grid.sync).
__device__ unsigned g_flags[256 * FSTRIDE];

__device__ __forceinline__ int map_gcol(int col, int jb) {
    if (col < 24) return col;              // master logit columns 0..23
    int r = col - 24;
    int blk = r / 24;                      // 0=f,1=i,2=o,3=cin
    int jj = r - blk * 24;
    return 24 + blk * Hsz + jb + jj;
}

__device__ __forceinline__ float sigm(float v) { return 1.0f / (1.0f + expf(-v)); }

__device__ __forceinline__ float ldf(const void* p, size_t i, bool f32) {
    return f32 ? ((const float*)p)[i] : (float)((const bf16*)p)[i];
}

__global__ __launch_bounds__(256) void stagenet_kernel(
    const void* __restrict__ x, const void* __restrict__ tim,
    const void* __restrict__ Wk, const void* __restrict__ bk,
    const void* __restrict__ Wr, const void* __restrict__ br,
    void* __restrict__ out)
{
    extern __shared__ char smem[];
    bf16*  Bl = (bf16*)(smem + OFF_B);
    bf16*  Al = (bf16*)(smem + OFF_A);
    float* Cl = (float*)(smem + OFF_A);   // aliases Al (after GEMM reads done)
    float* FM = (float*)(smem + OFF_FM);
    float* IM = (float*)(smem + OFF_IM);
    float* TB = (float*)(smem + OFF_TB);
    float* WL = (float*)(smem + OFF_WL);
    float* BI = (float*)(smem + OFF_BI);
    float* CS = (float*)(smem + OFF_CS);

    const int tid = threadIdx.x;
    const int wg  = blockIdx.x;
    const int mg  = wg >> 4;
    const int ng  = wg & 15;
    const int b0  = mg * MT;
    const int jb  = ng * JT;
    const int grp = mg * 16;              // first wg of my sync group

    // ---- runtime dtype detection (proved correct in round 2): fp32 data read
    // as bf16 shows random exponents in the low half-words of each float ----
    int insane = 0;
    {
        const unsigned short* wb = (const unsigned short*)Wk;
        for (int i = 0; i < 64; ++i) {
            unsigned short u = wb[i];
            int e = (u >> 7) & 0xFF;
            if ((e < 90 || e > 140) && u != 0) insane++;
        }
    }
    const bool isF32 = insane > 8;

    // ---- one-time: weight slice -> LDS bf16, B[n][k] layout ----
    for (int u = tid; u < NCOL * Ksz; u += 256) {
        int col = u & (NCOL - 1);
        int k   = u >> 7;
        bf16 v = (bf16)0.0f;
        if (col < 120) {
            int gcol = map_gcol(col, jb);
            float f = (k < Dsz) ? ldf(Wk, (size_t)k * Gsz + gcol, isF32)
                                : ldf(Wr, (size_t)(k - Dsz) * Gsz + gcol, isF32);
            v = (bf16)f;
        }
        Bl[col * STR + k] = v;
    }
    for (int col = tid; col < NCOL; col += 256) {
        float wl = 0.f, bi = 0.f;
        if (col < 120) {
            int gcol = map_gcol(col, jb);
            wl = ldf(Wk, (size_t)Dsz * Gsz + gcol, isF32) + ldf(Wr, (size_t)Hsz * Gsz + gcol, isF32);
            bi = ldf(bk, gcol, isF32) + ldf(br, gcol, isF32);
        }
        WL[col] = wl; BI[col] = bi;
    }
    for (int i = tid; i < MT * JT; i += 256) CS[i] = 0.f;

    // re-zero my flag every launch (monotone counter within a launch)
    if (tid == 0)
        __hip_atomic_store(&g_flags[wg * FSTRIDE], 0u,
                           __ATOMIC_RELAXED, __HIP_MEMORY_SCOPE_AGENT);

    cg::grid_group grid = cg::this_grid();
    grid.sync();   // one-time: zeroed flags visible to all before any polling

    const int lane = tid & 63;
    const int wv   = tid >> 6;
    const int m16  = lane & 15;
    const int quad = lane >> 4;
    const int n0   = (2 * wv) * 16 + m16;
    const int n1   = (2 * wv + 1) * 16 + m16;

    for (int t = 0; t < Tsz; ++t) {
        // ---- wait for group's h_{t-1}: 16-WG flag barrier, wave 0 polls ----
        if (t > 0) {
            if (wv == 0) {
                const unsigned target = (unsigned)t;
                unsigned v = target;
                for (;;) {
                    if (lane < 16)
                        v = __hip_atomic_load(&g_flags[(grp + lane) * FSTRIDE],
                                              __ATOMIC_RELAXED, __HIP_MEMORY_SCOPE_AGENT);
                    if (!__any(v < target)) break;
                    __builtin_amdgcn_s_sleep(2);
                }
                __builtin_amdgcn_fence(__ATOMIC_ACQUIRE, "agent");  // inv stale h lines
            }
            __syncthreads();   // other waves' h loads ordered after the inv
        }

        // ---- stage A = [x_t | h_{t-1}] (16 x 512) as bf16; h lives in out ----
        for (int u = tid; u < MT * 64; u += 256) {
            int m = u >> 6, q = u & 63;
            bf16x8 val;
            if (q < 16) {
                size_t base = ((size_t)(b0 + m) * Tsz + t) * Dsz + q * 8;
                if (isF32) {
                    const float* s = (const float*)x + base;
                    #pragma unroll
                    for (int j = 0; j < 8; ++j) val[j] = (bf16)s[j];
                } else {
                    val = *(const bf16x8*)((const bf16*)x + base);
                }
            } else if (t == 0) {
                #pragma unroll
                for (int j = 0; j < 8; ++j) val[j] = (bf16)0.0f;
            } else {
                size_t base = ((size_t)(b0 + m) * Tsz + (t - 1)) * Hsz + (q - 16) * 8;
                if (isF32) {
                    const float* s = (const float*)out + base;
                    #pragma unroll
                    for (int j = 0; j < 8; ++j) val[j] = (bf16)s[j];
                } else {
                    val = *(const bf16x8*)((const bf16*)out + base);
                }
            }
            *(bf16x8*)(Al + m * STR + q * 8) = val;
        }
        if (tid < MT) TB[tid] = ldf(tim, (size_t)(b0 + tid) * Tsz + t, isF32);
        __syncthreads();

        // ---- GEMM (16x512)@(512x128): 4 waves x 2 N-tiles ----
        f32x4 a0 = {0.f, 0.f, 0.f, 0.f}, a1 = {0.f, 0.f, 0.f, 0.f};
        #pragma unroll
        for (int ks = 0; ks < 16; ++ks) {
            bf16x8 av  = *(const bf16x8*)(Al + m16 * STR + ks * 32 + quad * 8);
            bf16x8 bv0 = *(const bf16x8*)(Bl + n0 * STR + ks * 32 + quad * 8);
            bf16x8 bv1 = *(const bf16x8*)(Bl + n1 * STR + ks * 32 + quad * 8);
            a0 = __builtin_amdgcn_mfma_f32_16x16x32_bf16(av, bv0, a0, 0, 0, 0);
            a1 = __builtin_amdgcn_mfma_f32_16x16x32_bf16(av, bv1, a1, 0, 0, 0);
        }
        __syncthreads();   // all A/B LDS reads done before aliased C write

        #pragma unroll
        for (int r = 0; r < 4; ++r) {
            Cl[(quad * 4 + r) * CST + (2 * wv) * 16 + m16]     = a0[r];
            Cl[(quad * 4 + r) * CST + (2 * wv + 1) * 16 + m16] = a1[r];
        }
        __syncthreads();

        // ---- masters: softmax + cumsum over L=12, one thread per batch ----
        if (tid < MT) {
            const int m = tid;
            const float tb = TB[m];
            float z[24];
            #pragma unroll
            for (int i = 0; i < 24; ++i)
                z[i] = Cl[m * CST + i] + BI[i] + tb * WL[i];
            float mx = z[0];
            #pragma unroll
            for (int i = 1; i < 12; ++i) mx = fmaxf(mx, z[i]);
            float e[12], s = 0.f;
            #pragma unroll
            for (int i = 0; i < 12; ++i) { e[i] = expf(z[i] - mx); s += e[i]; }
            float inv = 1.f / s, run = 0.f;
            #pragma unroll
            for (int i = 0; i < 12; ++i) { run += e[i]; FM[m * Lsz + i] = run * inv; }
            mx = z[12];
            #pragma unroll
            for (int i = 13; i < 24; ++i) mx = fmaxf(mx, z[i]);
            s = 0.f;
            #pragma unroll
            for (int i = 0; i < 12; ++i) { e[i] = expf(z[12 + i] - mx); s += e[i]; }
            inv = 1.f / s; run = 0.f;
            #pragma unroll
            for (int i = 11; i >= 0; --i) { run += e[i]; IM[m * Lsz + i] = run * inv; }
        }
        __syncthreads();

        // ---- gates + state update: 16 batches x 24 channels ----
        for (int fi = tid; fi < MT * JT; fi += 256) {
            int m = fi / JT;
            int j = fi - m * JT;
            int gj = jb + j;
            int l = gj >> 5;               // C = 32
            float tb = TB[m];
            float vf = Cl[m * CST + 24 + j] + BI[24 + j] + tb * WL[24 + j];
            float vi = Cl[m * CST + 48 + j] + BI[48 + j] + tb * WL[48 + j];
            float vo = Cl[m * CST + 72 + j] + BI[72 + j] + tb * WL[72 + j];
            float vc = Cl[m * CST + 96 + j] + BI[96 + j] + tb * WL[96 + j];
            float fg = sigm(vf);
            float ig = sigm(vi);
            float og = sigm(vo);
            float ci = tanhf(vc);
            float fm = FM[m * Lsz + l];
            float im = IM[m * Lsz + l];
            float ov = fm * im;
            float co = CS[fi];
            float cn = ov * (fg * co + ig * ci) + (fm - ov) * co + (im - ov) * ci;
            CS[fi] = cn;
            float hv = og * tanhf(cn);
            size_t oidx = ((size_t)(b0 + m) * Tsz + t) * Hsz + gj;
            if (isF32) ((float*)out)[oidx] = hv;
            else       ((bf16*)out)[oidx] = (bf16)hv;
        }

        // ---- publish h_t: drain all waves' stores, then RELEASE flag store ----
        if (t < Tsz - 1) {
            __builtin_amdgcn_s_waitcnt(0);   // this wave's vmem stores at L2
            __syncthreads();                 // all waves' h stores drained
            if (tid == 0)
                __hip_atomic_store(&g_flags[wg * FSTRIDE], (unsigned)(t + 1),
                                   __ATOMIC_RELEASE, __HIP_MEMORY_SCOPE_AGENT);
        }
    }
}

extern "C" void kernel_launch(void* const* d_in, const int* in_sizes, int n_in,
                              void* d_out, int out_size, void* d_ws, size_t ws_size,
                              hipStream_t stream) {
    const void* x  = d_in[0];
    const void* tm = d_in[1];
    const void* Wk = d_in[2];
    const void* bk = d_in[3];
    const void* Wr = d_in[4];
    const void* br = d_in[5];

    hipFuncSetAttribute(reinterpret_cast<const void*>(&stagenet_kernel),
                        hipFuncAttributeMaxDynamicSharedMemorySize, SMEM_BYTES);

    void* args[] = {(void*)&x, (void*)&tm, (void*)&Wk, (void*)&bk,
                    (void*)&Wr, (void*)&br, (void*)&d_out};
    hipLaunchCooperativeKernel(stagenet_kernel, dim3(256), dim3(256),
                               args, SMEM_BYTES, stream);
}

// Round 6
// 1764.643 us; speedup vs baseline: 8.7356x; 1.8354x over previous
//
#include <hip/hip_runtime.h>
#include <hip/hip_cooperative_groups.h>

namespace cg = cooperative_groups;

typedef __bf16 bf16;
typedef __bf16 bf16x8 __attribute__((ext_vector_type(8)));
typedef float f32x4 __attribute__((ext_vector_type(4)));

#define Bsz 256
#define Tsz 256
#define Dsz 128
#define Hsz 384
#define Lsz 12
#define Gsz 1560
#define Ksz 512
#define STR 520      // padded k-stride (elems)
#define NCOL 128     // padded per-WG columns (120 real)
#define CST 132      // C_lds row stride (fp32 elems)
#define MT 16        // batches per WG
#define JT 24        // channels per WG
#define FSTRIDE 32   // flag stride in dwords (128B)

// LDS layout (bytes). Bl (weights) is dead after B-fragment hoist -> C scratch
// reuses its region (no aliasing with A staging => one fewer barrier).
#define OFF_B   0
#define OFF_A   (NCOL*STR*2)              // 133120
#define OFF_FM  (OFF_A + MT*STR*2)        // +16640
#define OFF_IM  (OFF_FM + MT*Lsz*4)
#define OFF_TB  (OFF_IM + MT*Lsz*4)
#define OFF_WL  (OFF_TB + MT*4)
#define OFF_BI  (OFF_WL + NCOL*4)
#define OFF_CS  (OFF_BI + NCOL*4)
#define SMEM_BYTES (OFF_CS + MT*JT*4)     // 153920

// Flags in module .bss (d_ws unused). Re-zeroed at top of every launch.
__device__ unsigned g_flags[256 * FSTRIDE];

__device__ __forceinline__ int map_gcol(int col, int jb) {
    if (col < 24) return col;              // master logit columns 0..23
    int r = col - 24;
    int blk = r / 24;                      // 0=f,1=i,2=o,3=cin
    int jj = r - blk * 24;
    return 24 + blk * Hsz + jb + jj;
}

__device__ __forceinline__ float sigm(float v) { return 1.0f / (1.0f + expf(-v)); }

__device__ __forceinline__ float ldf(const void* p, size_t i, bool f32) {
    return f32 ? ((const float*)p)[i] : (float)((const bf16*)p)[i];
}

__global__ __launch_bounds__(256, 1) void stagenet_kernel(
    const void* __restrict__ x, const void* __restrict__ tim,
    const void* __restrict__ Wk, const void* __restrict__ bk,
    const void* __restrict__ Wr, const void* __restrict__ br,
    void* __restrict__ out)
{
    extern __shared__ char smem[];
    bf16*  Bl = (bf16*)(smem + OFF_B);
    float* Cl = (float*)(smem + OFF_B);   // reuses weight region (dead after hoist)
    bf16*  Al = (bf16*)(smem + OFF_A);
    float* FM = (float*)(smem + OFF_FM);
    float* IM = (float*)(smem + OFF_IM);
    float* TB = (float*)(smem + OFF_TB);
    float* WL = (float*)(smem + OFF_WL);
    float* BI = (float*)(smem + OFF_BI);
    float* CS = (float*)(smem + OFF_CS);

    const int tid = threadIdx.x;
    const int wg  = blockIdx.x;
    const int mg  = wg >> 4;
    const int ng  = wg & 15;
    const int b0  = mg * MT;
    const int jb  = ng * JT;
    const int grp = mg * 16;              // first wg of my sync group

    // ---- runtime dtype detection (fp32 confirmed in rounds 2/5; keep hedge) ----
    int insane = 0;
    {
        const unsigned short* wb = (const unsigned short*)Wk;
        for (int i = 0; i < 64; ++i) {
            unsigned short u = wb[i];
            int e = (u >> 7) & 0xFF;
            if ((e < 90 || e > 140) && u != 0) insane++;
        }
    }
    const bool isF32 = insane > 8;

    // ---- one-time: weight slice -> LDS bf16, B[n][k] layout ----
    for (int u = tid; u < NCOL * Ksz; u += 256) {
        int col = u & (NCOL - 1);
        int k   = u >> 7;
        bf16 v = (bf16)0.0f;
        if (col < 120) {
            int gcol = map_gcol(col, jb);
            float f = (k < Dsz) ? ldf(Wk, (size_t)k * Gsz + gcol, isF32)
                                : ldf(Wr, (size_t)(k - Dsz) * Gsz + gcol, isF32);
            v = (bf16)f;
        }
        Bl[col * STR + k] = v;
    }
    for (int col = tid; col < NCOL; col += 256) {
        float wl = 0.f, bi = 0.f;
        if (col < 120) {
            int gcol = map_gcol(col, jb);
            wl = ldf(Wk, (size_t)Dsz * Gsz + gcol, isF32) + ldf(Wr, (size_t)Hsz * Gsz + gcol, isF32);
            bi = ldf(bk, gcol, isF32) + ldf(br, gcol, isF32);
        }
        WL[col] = wl; BI[col] = bi;
    }
    for (int i = tid; i < MT * JT; i += 256) CS[i] = 0.f;

    if (tid == 0)
        __hip_atomic_store(&g_flags[wg * FSTRIDE], 0u,
                           __ATOMIC_RELAXED, __HIP_MEMORY_SCOPE_AGENT);

    __syncthreads();
    cg::grid_group grid = cg::this_grid();
    grid.sync();   // zeroed flags + staged weights visible
    // ONE-TIME inv: drop any lines cached by a previous graph replay of this
    // kernel. Within the launch, h lines are first-touched only after their
    // producer's write-through store reached the LLC -> no per-step inv needed.
    __builtin_amdgcn_fence(__ATOMIC_ACQUIRE, "agent");

    const int lane = tid & 63;
    const int wv   = tid >> 6;
    const int m16  = lane & 15;
    const int quad = lane >> 4;
    const int n0   = (2 * wv) * 16 + m16;
    const int n1   = (2 * wv + 1) * 16 + m16;

    // ---- hoist B fragments (t-invariant) into registers: 128 VGPRs ----
    bf16x8 Bf0[16], Bf1[16];
    #pragma unroll
    for (int ks = 0; ks < 16; ++ks) {
        Bf0[ks] = *(const bf16x8*)(Bl + n0 * STR + ks * 32 + quad * 8);
        Bf1[ks] = *(const bf16x8*)(Bl + n1 * STR + ks * 32 + quad * 8);
    }
    __syncthreads();   // Bl reads done; region now reusable as Cl

    for (int t = 0; t < Tsz; ++t) {
        // ---- stage x-part of A (overlaps the poll); h-zeros at t=0 ----
        {
            int m = tid >> 4, q = tid & 15;      // 256 threads = 16x16 chunks
            bf16x8 val;
            size_t base = ((size_t)(b0 + m) * Tsz + t) * Dsz + q * 8;
            if (isF32) {
                const float* s = (const float*)x + base;
                #pragma unroll
                for (int j = 0; j < 8; ++j) val[j] = (bf16)s[j];
            } else {
                val = *(const bf16x8*)((const bf16*)x + base);
            }
            *(bf16x8*)(Al + m * STR + q * 8) = val;
        }
        if (t == 0) {
            for (int u = tid; u < MT * 48; u += 256) {
                int m = u / 48, q = u - m * 48;
                bf16x8 z;
                #pragma unroll
                for (int j = 0; j < 8; ++j) z[j] = (bf16)0.0f;
                *(bf16x8*)(Al + m * STR + 128 + q * 8) = z;
            }
        }
        if (tid < MT) TB[tid] = ldf(tim, (size_t)(b0 + tid) * Tsz + t, isF32);

        // ---- wait for group's h_{t-1}: wave 0 polls 16 flags ----
        if (t > 0) {
            if (wv == 0) {
                const unsigned target = (unsigned)t;
                unsigned v = target;
                for (;;) {
                    if (lane < 16)
                        v = __hip_atomic_load(&g_flags[(grp + lane) * FSTRIDE],
                                              __ATOMIC_RELAXED, __HIP_MEMORY_SCOPE_AGENT);
                    if (!__any(v < target)) break;
                    __builtin_amdgcn_s_sleep(1);
                }
            }
            __syncthreads();   // barrier orders everyone's h loads after the poll

            // ---- stage h-part of A (fresh lines, fetched from LLC) ----
            for (int u = tid; u < MT * 48; u += 256) {
                int m = u / 48, q = u - m * 48;
                bf16x8 val;
                size_t base = ((size_t)(b0 + m) * Tsz + (t - 1)) * Hsz + q * 8;
                if (isF32) {
                    const float* s = (const float*)out + base;
                    #pragma unroll
                    for (int j = 0; j < 8; ++j) val[j] = (bf16)s[j];
                } else {
                    val = *(const bf16x8*)((const bf16*)out + base);
                }
                *(bf16x8*)(Al + m * STR + 128 + q * 8) = val;
            }
        }
        __syncthreads();   // all A staging visible

        // ---- GEMM (16x512)@(512x128): A from LDS, B from registers ----
        f32x4 a0 = {0.f, 0.f, 0.f, 0.f}, a1 = {0.f, 0.f, 0.f, 0.f};
        #pragma unroll
        for (int ks = 0; ks < 16; ++ks) {
            bf16x8 av = *(const bf16x8*)(Al + m16 * STR + ks * 32 + quad * 8);
            a0 = __builtin_amdgcn_mfma_f32_16x16x32_bf16(av, Bf0[ks], a0, 0, 0, 0);
            a1 = __builtin_amdgcn_mfma_f32_16x16x32_bf16(av, Bf1[ks], a1, 0, 0, 0);
        }

        // C scratch lives in the dead weight region — no conflict with Al
        #pragma unroll
        for (int r = 0; r < 4; ++r) {
            Cl[(quad * 4 + r) * CST + (2 * wv) * 16 + m16]     = a0[r];
            Cl[(quad * 4 + r) * CST + (2 * wv + 1) * 16 + m16] = a1[r];
        }
        __syncthreads();

        // ---- masters: softmax + cumsum over L=12, one thread per batch ----
        if (tid < MT) {
            const int m = tid;
            const float tb = TB[m];
            float z[24];
            #pragma unroll
            for (int i = 0; i < 24; ++i)
                z[i] = Cl[m * CST + i] + BI[i] + tb * WL[i];
            float mx = z[0];
            #pragma unroll
            for (int i = 1; i < 12; ++i) mx = fmaxf(mx, z[i]);
            float e[12], s = 0.f;
            #pragma unroll
            for (int i = 0; i < 12; ++i) { e[i] = expf(z[i] - mx); s += e[i]; }
            float inv = 1.f / s, run = 0.f;
            #pragma unroll
            for (int i = 0; i < 12; ++i) { run += e[i]; FM[m * Lsz + i] = run * inv; }
            mx = z[12];
            #pragma unroll
            for (int i = 13; i < 24; ++i) mx = fmaxf(mx, z[i]);
            s = 0.f;
            #pragma unroll
            for (int i = 0; i < 12; ++i) { e[i] = expf(z[12 + i] - mx); s += e[i]; }
            inv = 1.f / s; run = 0.f;
            #pragma unroll
            for (int i = 11; i >= 0; --i) { run += e[i]; IM[m * Lsz + i] = run * inv; }
        }
        __syncthreads();

        // ---- gates + state update; h stores are WRITE-THROUGH (agent atomics)
        //      so they are visible at the LLC without any release fence ----
        for (int fi = tid; fi < MT * JT; fi += 256) {
            int m = fi / JT;
            int j = fi - m * JT;
            int gj = jb + j;
            int l = gj >> 5;               // C = 32
            float tb = TB[m];
            float vf = Cl[m * CST + 24 + j] + BI[24 + j] + tb * WL[24 + j];
            float vi = Cl[m * CST + 48 + j] + BI[48 + j] + tb * WL[48 + j];
            float vo = Cl[m * CST + 72 + j] + BI[72 + j] + tb * WL[72 + j];
            float vc = Cl[m * CST + 96 + j] + BI[96 + j] + tb * WL[96 + j];
            float fg = sigm(vf);
            float ig = sigm(vi);
            float og = sigm(vo);
            float ci = tanhf(vc);
            float fm = FM[m * Lsz + l];
            float im = IM[m * Lsz + l];
            float ov = fm * im;
            float co = CS[fi];
            float cn = ov * (fg * co + ig * ci) + (fm - ov) * co + (im - ov) * ci;
            CS[fi] = cn;
            float hv = og * tanhf(cn);
            size_t oidx = ((size_t)(b0 + m) * Tsz + t) * Hsz + gj;
            if (isF32) {
                __hip_atomic_store((float*)out + oidx, hv,
                                   __ATOMIC_RELAXED, __HIP_MEMORY_SCOPE_AGENT);
            } else {
                bf16 hb = (bf16)hv;
                __hip_atomic_store((unsigned short*)out + oidx,
                                   __builtin_bit_cast(unsigned short, hb),
                                   __ATOMIC_RELAXED, __HIP_MEMORY_SCOPE_AGENT);
            }
        }

        // ---- publish: drain stores (acked at LLC), then flag ----
        if (t < Tsz - 1) {
            __builtin_amdgcn_s_waitcnt(0);   // this wave's stores reached LLC
            __syncthreads();                 // all waves drained
            if (tid == 0)
                __hip_atomic_store(&g_flags[wg * FSTRIDE], (unsigned)(t + 1),
                                   __ATOMIC_RELAXED, __HIP_MEMORY_SCOPE_AGENT);
        }
    }
}

extern "C" void kernel_launch(void* const* d_in, const int* in_sizes, int n_in,
                              void* d_out, int out_size, void* d_ws, size_t ws_size,
                              hipStream_t stream) {
    const void* x  = d_in[0];
    const void* tm = d_in[1];
    const void* Wk = d_in[2];
    const void* bk = d_in[3];
    const void* Wr = d_in[4];
    const void* br = d_in[5];

    hipFuncSetAttribute(reinterpret_cast<const void*>(&stagenet_kernel),
                        hipFuncAttributeMaxDynamicSharedMemorySize, SMEM_BYTES);

    void* args[] = {(void*)&x, (void*)&tm, (void*)&Wk, (void*)&bk,
                    (void*)&Wr, (void*)&br, (void*)&d_out};
    hipLaunchCooperativeKernel(stagenet_kernel, dim3(256), dim3(256),
                               args, SMEM_BYTES, stream);
}

// Round 7
// 1711.892 us; speedup vs baseline: 9.0048x; 1.0308x over previous
//
#include <hip/hip_runtime.h>
#include <hip/hip_cooperative_groups.h>

namespace cg = cooperative_groups;

typedef __bf16 bf16;
typedef __bf16 bf16x8 __attribute__((ext_vector_type(8)));
typedef float f32x4 __attribute__((ext_vector_type(4)));
typedef unsigned long long u64;

#define Bsz 256
#define Tsz 256
#define Dsz 128
#define Hsz 384
#define Lsz 12
#define Gsz 1560
#define Ksz 512
#define STR 520      // padded k-stride (elems)
#define NCOL 128     // padded per-WG columns (120 real)
#define CST 132      // C_lds row stride (fp32 elems)
#define MT 16        // batches per WG
#define JT 24        // channels per WG
#define FSTRIDE 32   // flag stride in dwords (fallback path)
#define NBLK 128     // 8B exchange blocks per batch (3 bf16 ch + u16 tag)
#define SLOTS 4      // slot ring; producer lead is provably <=2, 4 is safe
#define EXCH_BYTES ((size_t)SLOTS * Bsz * NBLK * 8)   // 1 MiB

// LDS layout (bytes). Weight region is dead after B-frag hoist -> C scratch.
#define OFF_B   0
#define OFF_A   (NCOL*STR*2)              // 133120
#define OFF_FM  (OFF_A + MT*STR*2)
#define OFF_IM  (OFF_FM + MT*Lsz*4)
#define OFF_TB  (OFF_IM + MT*Lsz*4)
#define OFF_WL  (OFF_TB + MT*4)
#define OFF_BI  (OFF_WL + NCOL*4)
#define OFF_CS  (OFF_BI + NCOL*4)
#define OFF_HS  (OFF_CS + MT*JT*4)        // u16 h staging for packing
#define SMEM_BYTES (OFF_HS + MT*26*2)     // 154752

__device__ unsigned g_flags[256 * FSTRIDE];   // fallback protocol only

__device__ __forceinline__ int map_gcol(int col, int jb) {
    if (col < 24) return col;              // master logit columns 0..23
    int r = col - 24;
    int blk = r / 24;                      // 0=f,1=i,2=o,3=cin
    int jj = r - blk * 24;
    return 24 + blk * Hsz + jb + jj;
}

// fast transcendentals: hw v_exp_f32 based; error ~1e-6 rel << bf16 rounding
__device__ __forceinline__ float sigm(float v) { return 1.0f / (1.0f + __expf(-v)); }
__device__ __forceinline__ float ftanh(float v) {
    float xc = fminf(fmaxf(v, -10.f), 10.f);   // clamp: avoid inf/inf
    float e = __expf(2.f * xc);
    return (e - 1.f) / (e + 1.f);
}

__device__ __forceinline__ float ldf(const void* p, size_t i, bool f32) {
    return f32 ? ((const float*)p)[i] : (float)((const bf16*)p)[i];
}

__global__ __launch_bounds__(256, 1) void stagenet_kernel(
    const void* __restrict__ x, const void* __restrict__ tim,
    const void* __restrict__ Wk, const void* __restrict__ bk,
    const void* __restrict__ Wr, const void* __restrict__ br,
    void* __restrict__ out, u64* __restrict__ exch)
{
    extern __shared__ char smem[];
    bf16*  Bl = (bf16*)(smem + OFF_B);
    float* Cl = (float*)(smem + OFF_B);   // reuses weight region (dead after hoist)
    bf16*  Al = (bf16*)(smem + OFF_A);
    float* FM = (float*)(smem + OFF_FM);
    float* IM = (float*)(smem + OFF_IM);
    float* TB = (float*)(smem + OFF_TB);
    float* WL = (float*)(smem + OFF_WL);
    float* BI = (float*)(smem + OFF_BI);
    float* CS = (float*)(smem + OFF_CS);
    unsigned short* HS = (unsigned short*)(smem + OFF_HS);

    const int tid = threadIdx.x;
    const int wg  = blockIdx.x;
    const int mg  = wg >> 4;
    const int ng  = wg & 15;
    const int b0  = mg * MT;
    const int jb  = ng * JT;
    const int grp = mg * 16;
    const bool useEx = (exch != nullptr);

    // ---- runtime dtype detection (fp32 confirmed; keep hedge) ----
    int insane = 0;
    {
        const unsigned short* wb = (const unsigned short*)Wk;
        for (int i = 0; i < 64; ++i) {
            unsigned short u = wb[i];
            int e = (u >> 7) & 0xFF;
            if ((e < 90 || e > 140) && u != 0) insane++;
        }
    }
    const bool isF32 = insane > 8;

    // ---- one-time: weight slice -> LDS bf16, B[n][k] layout ----
    for (int u = tid; u < NCOL * Ksz; u += 256) {
        int col = u & (NCOL - 1);
        int k   = u >> 7;
        bf16 v = (bf16)0.0f;
        if (col < 120) {
            int gcol = map_gcol(col, jb);
            float f = (k < Dsz) ? ldf(Wk, (size_t)k * Gsz + gcol, isF32)
                                : ldf(Wr, (size_t)(k - Dsz) * Gsz + gcol, isF32);
            v = (bf16)f;
        }
        Bl[col * STR + k] = v;
    }
    for (int col = tid; col < NCOL; col += 256) {
        float wl = 0.f, bi = 0.f;
        if (col < 120) {
            int gcol = map_gcol(col, jb);
            wl = ldf(Wk, (size_t)Dsz * Gsz + gcol, isF32) + ldf(Wr, (size_t)Hsz * Gsz + gcol, isF32);
            bi = ldf(bk, gcol, isF32) + ldf(br, gcol, isF32);
        }
        WL[col] = wl; BI[col] = bi;
    }
    for (int i = tid; i < MT * JT; i += 256) CS[i] = 0.f;

    if (!useEx) {
        // fallback flag protocol needs zeroed flags published grid-wide
        if (tid == 0)
            __hip_atomic_store(&g_flags[wg * FSTRIDE], 0u,
                               __ATOMIC_RELAXED, __HIP_MEMORY_SCOPE_AGENT);
        __syncthreads();
        cg::grid_group grid = cg::this_grid();
        grid.sync();
        __builtin_amdgcn_fence(__ATOMIC_ACQUIRE, "agent");
    } else {
        __syncthreads();   // Bl staged before hoist reads
    }

    const int lane = tid & 63;
    const int wv   = tid >> 6;
    const int m16  = lane & 15;
    const int quad = lane >> 4;
    const int n0   = (2 * wv) * 16 + m16;
    const int n1   = (2 * wv + 1) * 16 + m16;

    // ---- hoist B fragments (t-invariant) into registers/AGPRs ----
    bf16x8 Bf0[16], Bf1[16];
    #pragma unroll
    for (int ks = 0; ks < 16; ++ks) {
        Bf0[ks] = *(const bf16x8*)(Bl + n0 * STR + ks * 32 + quad * 8);
        Bf1[ks] = *(const bf16x8*)(Bl + n1 * STR + ks * 32 + quad * 8);
    }
    __syncthreads();   // Bl reads done; region now reusable as Cl

    for (int t = 0; t < Tsz; ++t) {
        // ---- stage x-part of A (loads overlap the h wait below) ----
        {
            int m = tid >> 4, q = tid & 15;      // 256 threads = 16x16 chunks
            bf16x8 val;
            size_t base = ((size_t)(b0 + m) * Tsz + t) * Dsz + q * 8;
            if (isF32) {
                const float* s = (const float*)x + base;
                #pragma unroll
                for (int j = 0; j < 8; ++j) val[j] = (bf16)s[j];
            } else {
                val = *(const bf16x8*)((const bf16*)x + base);
            }
            *(bf16x8*)(Al + m * STR + q * 8) = val;
        }
        if (t == 0) {
            for (int u = tid; u < MT * 48; u += 256) {
                int m = u / 48, q = u - m * 48;
                bf16x8 z;
                #pragma unroll
                for (int j = 0; j < 8; ++j) z[j] = (bf16)0.0f;
                *(bf16x8*)(Al + m * STR + 128 + q * 8) = z;
            }
        }
        if (tid < MT) TB[tid] = ldf(tim, (size_t)(b0 + tid) * Tsz + t, isF32);

        // ---- acquire h_{t-1} ----
        if (t > 0) {
            if (useEx) {
                // poll tagged 8B blocks directly: tag match => data in register
                const int slot = (t - 1) & (SLOTS - 1);
                const unsigned want = (unsigned)(t - 1);
                const u64* pp[8];
                u64 v[8];
                #pragma unroll
                for (int i = 0; i < 8; ++i) {
                    int g = tid + 256 * i;          // g in [0, 2048)
                    int m = g >> 7, blk = g & 127;
                    pp[i] = &exch[((size_t)slot * Bsz + (b0 + m)) * NBLK + blk];
                    v[i] = __hip_atomic_load(pp[i], __ATOMIC_RELAXED,
                                             __HIP_MEMORY_SCOPE_AGENT);
                }
                unsigned pend = 0xFFu;
                while (pend) {
                    #pragma unroll
                    for (int i = 0; i < 8; ++i) {
                        if ((pend >> i) & 1) {
                            if ((unsigned)(v[i] >> 48) == want) {
                                int g = tid + 256 * i;
                                int m = g >> 7, blk = g & 127;
                                unsigned short* d =
                                    (unsigned short*)(Al + m * STR + 128 + blk * 3);
                                d[0] = (unsigned short)v[i];
                                d[1] = (unsigned short)(v[i] >> 16);
                                d[2] = (unsigned short)(v[i] >> 32);
                                pend &= ~(1u << i);
                            } else {
                                v[i] = __hip_atomic_load(pp[i], __ATOMIC_RELAXED,
                                                         __HIP_MEMORY_SCOPE_AGENT);
                            }
                        }
                    }
                }
            } else {
                // fallback: flag barrier + reload h from out
                if (wv == 0) {
                    const unsigned target = (unsigned)t;
                    unsigned v = target;
                    for (;;) {
                        if (lane < 16)
                            v = __hip_atomic_load(&g_flags[(grp + lane) * FSTRIDE],
                                                  __ATOMIC_RELAXED, __HIP_MEMORY_SCOPE_AGENT);
                        if (!__any(v < target)) break;
                        __builtin_amdgcn_s_sleep(1);
                    }
                }
                __syncthreads();
                for (int u = tid; u < MT * 48; u += 256) {
                    int m = u / 48, q = u - m * 48;
                    bf16x8 val;
                    size_t base = ((size_t)(b0 + m) * Tsz + (t - 1)) * Hsz + q * 8;
                    if (isF32) {
                        const float* s = (const float*)out + base;
                        #pragma unroll
                        for (int j = 0; j < 8; ++j) val[j] = (bf16)s[j];
                    } else {
                        val = *(const bf16x8*)((const bf16*)out + base);
                    }
                    *(bf16x8*)(Al + m * STR + 128 + q * 8) = val;
                }
            }
        }
        __syncthreads();   // S1: all A staging visible

        // ---- GEMM (16x512)@(512x128): A from LDS, B from registers ----
        f32x4 a0 = {0.f, 0.f, 0.f, 0.f}, a1 = {0.f, 0.f, 0.f, 0.f};
        #pragma unroll
        for (int ks = 0; ks < 16; ++ks) {
            bf16x8 av = *(const bf16x8*)(Al + m16 * STR + ks * 32 + quad * 8);
            a0 = __builtin_amdgcn_mfma_f32_16x16x32_bf16(av, Bf0[ks], a0, 0, 0, 0);
            a1 = __builtin_amdgcn_mfma_f32_16x16x32_bf16(av, Bf1[ks], a1, 0, 0, 0);
        }
        #pragma unroll
        for (int r = 0; r < 4; ++r) {
            Cl[(quad * 4 + r) * CST + (2 * wv) * 16 + m16]     = a0[r];
            Cl[(quad * 4 + r) * CST + (2 * wv + 1) * 16 + m16] = a1[r];
        }
        __syncthreads();   // S2

        // ---- masters: softmax + cumsum over L=12, one thread per batch ----
        if (tid < MT) {
            const int m = tid;
            const float tb = TB[m];
            float z[24];
            #pragma unroll
            for (int i = 0; i < 24; ++i)
                z[i] = Cl[m * CST + i] + BI[i] + tb * WL[i];
            float mx = z[0];
            #pragma unroll
            for (int i = 1; i < 12; ++i) mx = fmaxf(mx, z[i]);
            float e[12], s = 0.f;
            #pragma unroll
            for (int i = 0; i < 12; ++i) { e[i] = __expf(z[i] - mx); s += e[i]; }
            float inv = 1.f / s, run = 0.f;
            #pragma unroll
            for (int i = 0; i < 12; ++i) { run += e[i]; FM[m * Lsz + i] = run * inv; }
            mx = z[12];
            #pragma unroll
            for (int i = 13; i < 24; ++i) mx = fmaxf(mx, z[i]);
            s = 0.f;
            #pragma unroll
            for (int i = 0; i < 12; ++i) { e[i] = __expf(z[12 + i] - mx); s += e[i]; }
            inv = 1.f / s; run = 0.f;
            #pragma unroll
            for (int i = 11; i >= 0; --i) { run += e[i]; IM[m * Lsz + i] = run * inv; }
        }
        __syncthreads();   // S3

        // ---- gates + state update ----
        for (int fi = tid; fi < MT * JT; fi += 256) {
            int m = fi / JT;
            int j = fi - m * JT;
            int gj = jb + j;
            int l = gj >> 5;               // C = 32
            float tb = TB[m];
            float vf = Cl[m * CST + 24 + j] + BI[24 + j] + tb * WL[24 + j];
            float vi = Cl[m * CST + 48 + j] + BI[48 + j] + tb * WL[48 + j];
            float vo = Cl[m * CST + 72 + j] + BI[72 + j] + tb * WL[72 + j];
            float vc = Cl[m * CST + 96 + j] + BI[96 + j] + tb * WL[96 + j];
            float fg = sigm(vf);
            float ig = sigm(vi);
            float og = sigm(vo);
            float ci = ftanh(vc);
            float fm = FM[m * Lsz + l];
            float im = IM[m * Lsz + l];
            float ov = fm * im;
            float co = CS[fi];
            float cn = ov * (fg * co + ig * ci) + (fm - ov) * co + (im - ov) * ci;
            CS[fi] = cn;
            float hv = og * ftanh(cn);
            bf16 hb = (bf16)hv;
            size_t oidx = ((size_t)(b0 + m) * Tsz + t) * Hsz + gj;
            if (useEx) {
                // plain out store (read only by host after kernel end)
                if (isF32) ((float*)out)[oidx] = hv;
                else       ((bf16*)out)[oidx] = hb;
                HS[m * 26 + j] = __builtin_bit_cast(unsigned short, hb);
            } else {
                // fallback: write-through so group partners see h without fences
                if (isF32) {
                    __hip_atomic_store((float*)out + oidx, hv,
                                       __ATOMIC_RELAXED, __HIP_MEMORY_SCOPE_AGENT);
                } else {
                    __hip_atomic_store((unsigned short*)out + oidx,
                                       __builtin_bit_cast(unsigned short, hb),
                                       __ATOMIC_RELAXED, __HIP_MEMORY_SCOPE_AGENT);
                }
            }
        }

        // ---- publish h_t ----
        if (useEx) {
            __syncthreads();   // S4: HS visible to packing threads
            if (t < Tsz - 1) {
                for (int u2 = tid; u2 < MT * 8; u2 += 256) {   // 128 blocks
                    int m = u2 >> 3, lb = u2 & 7;
                    const unsigned short* hs = &HS[m * 26 + lb * 3];
                    u64 vv = (u64)hs[0] | ((u64)hs[1] << 16) | ((u64)hs[2] << 32)
                           | ((u64)(unsigned)t << 48);
                    int blk = ng * 8 + lb;                     // jb/3 + lb
                    __hip_atomic_store(
                        &exch[((size_t)(t & (SLOTS - 1)) * Bsz + (b0 + m)) * NBLK + blk],
                        vv, __ATOMIC_RELAXED, __HIP_MEMORY_SCOPE_AGENT);
                }
            }
        } else {
            if (t < Tsz - 1) {
                __builtin_amdgcn_s_waitcnt(0);
                __syncthreads();
                if (tid == 0)
                    __hip_atomic_store(&g_flags[wg * FSTRIDE], (unsigned)(t + 1),
                                       __ATOMIC_RELAXED, __HIP_MEMORY_SCOPE_AGENT);
            }
        }
    }
}

extern "C" void kernel_launch(void* const* d_in, const int* in_sizes, int n_in,
                              void* d_out, int out_size, void* d_ws, size_t ws_size,
                              hipStream_t stream) {
    const void* x  = d_in[0];
    const void* tm = d_in[1];
    const void* Wk = d_in[2];
    const void* bk = d_in[3];
    const void* Wr = d_in[4];
    const void* br = d_in[5];
    // tagged-exchange path needs 1 MiB of scratch; poison 0xAA == invalid tag
    u64* exch = (ws_size >= EXCH_BYTES) ? (u64*)d_ws : nullptr;

    hipFuncSetAttribute(reinterpret_cast<const void*>(&stagenet_kernel),
                        hipFuncAttributeMaxDynamicSharedMemorySize, SMEM_BYTES);

    void* args[] = {(void*)&x, (void*)&tm, (void*)&Wk, (void*)&bk,
                    (void*)&Wr, (void*)&br, (void*)&d_out, (void*)&exch};
    hipLaunchCooperativeKernel(stagenet_kernel, dim3(256), dim3(256),
                               args, SMEM_BYTES, stream);
}